// Round 11
// baseline (367.998 us; speedup 1.0000x reference)
//
#include <hip/hip_runtime.h>
#include <hip/hip_cooperative_groups.h>
#include <math.h>

namespace cg = cooperative_groups;

typedef float f32x4 __attribute__((ext_vector_type(4)));
typedef __bf16 bf16x8 __attribute__((ext_vector_type(8)));
typedef unsigned short u16x8 __attribute__((ext_vector_type(8)));

__device__ __forceinline__ unsigned short f2bf(float f) {
  unsigned u = __float_as_uint(f);
  unsigned r = (u + 0x7fffu + ((u >> 16) & 1u)) >> 16;
  return (unsigned short)r;
}
__device__ __forceinline__ float bf2f(unsigned short h) {
  return __uint_as_float(((unsigned)h) << 16);
}

// ---------------- block reduction helper ----------------
__device__ __forceinline__ float blk_sum(float v, float* red, int tid) {
  #pragma unroll
  for (int o = 32; o; o >>= 1) v += __shfl_down(v, o);
  __syncthreads();
  if ((tid & 63) == 0) red[tid >> 6] = v;
  __syncthreads();
  return red[0] + red[1] + red[2] + red[3];
}

// ---------------- fused k_s + twiddle table + prep (cooperative, grid 1024) ----------------
// Phase A: blocks 0..31 = softmax(freq_w) + s = irfft(softmax) + Parseval weights (old k_s);
//          blocks 32..37 = fill 1344-entry twiddle table for k_ln (lane-indexed float2).
// grid.sync(); Phase B: grid-stride over 11264 jobs: cvt x / pw / dw, build circulant Sb.
__global__ __launch_bounds__(256, 4) void k_sprep(const float* __restrict__ fw,
                                                  const float* __restrict__ x,
                                                  const float* __restrict__ pw,
                                                  const float* __restrict__ dw,
                                                  float* __restrict__ s,
                                                  float* __restrict__ pwp,
                                                  float2* __restrict__ twtab,
                                                  unsigned short* __restrict__ xb,
                                                  unsigned short* __restrict__ pwb,
                                                  unsigned short* __restrict__ dwb,
                                                  unsigned short* __restrict__ Sb) {
  __shared__ float wsh[513];
  __shared__ float red[4];
  const int tid = threadIdx.x;

  if (blockIdx.x < 32) {
    // ---- old k_s body ----
    float m = -1e30f;
    for (int i = tid; i < 513; i += 256) m = fmaxf(m, fw[i]);
    #pragma unroll
    for (int o = 32; o; o >>= 1) m = fmaxf(m, __shfl_down(m, o));
    if ((tid & 63) == 0) red[tid >> 6] = m;
    __syncthreads();
    m = fmaxf(fmaxf(red[0], red[1]), fmaxf(red[2], red[3]));
    float sum = 0.f;
    for (int i = tid; i < 513; i += 256) {
      float e = expf(fw[i] - m);
      wsh[i] = e;
      sum += e;
    }
    sum = blk_sum(sum, red, tid);   // syncs inside -> wsh visible after
    float inv = 1.f / sum;

    if (blockIdx.x == 0) {
      for (int i = tid; i < 513; i += 256) {
        float wn = wsh[i] * inv;
        float cf = (i == 0 || i == 512) ? 1.f : 2.f;
        pwp[i] = cf * wn * wn * (1.f / 1024.f);
      }
    }

    int gid = blockIdx.x * 256 + tid;   // 8192 threads: d = gid>>3, chunk = gid&7
    int d = gid >> 3;
    int chunk = gid & 7;
    float acc = 0.f;
    for (int f = 1 + chunk; f < 512; f += 8) {
      int p = (f * d) & 1023;
      acc += wsh[f] * __cosf(6.283185307179586f * (float)p * (1.f / 1024.f));
    }
    acc += __shfl_xor(acc, 1);
    acc += __shfl_xor(acc, 2);
    acc += __shfl_xor(acc, 4);
    if (chunk == 0) {
      float tot = wsh[0] + ((d & 1) ? -wsh[512] : wsh[512]) + 2.f * acc;
      s[d] = tot * inv * (1.f / 1024.f);
    }
  } else if (blockIdx.x < 38) {
    // ---- twiddle table: 1344 float2 entries, same __cosf/__sinf as k_ln used ----
    int t = (int)(blockIdx.x - 32) * 256 + tid;
    if (t < 1344) {
      float ang;
      bool neg = false;
      if (t < 384) {                       // stages 1..6, pre-sign-folded
        int st = (t >> 6) + 1, l = t & 63;
        int half = 1 << (st - 1);
        int pos = l & (half - 1);
        ang = -3.14159265358979f * (float)pos / (float)half;
        neg = (l & half) != 0;
      } else if (t < 448) {                // stage 7: -pi*lane/64
        ang = -3.14159265358979f * (float)(t - 384) * (1.f / 64.f);
      } else if (t < 512) {                // stage 8a: -pi*lane/128
        ang = -3.14159265358979f * (float)(t - 448) * (1.f / 128.f);
      } else if (t < 576) {                // stage 8b: -pi*(64+lane)/128
        ang = -3.14159265358979f * (float)(64 + (t - 512)) * (1.f / 128.f);
      } else if (t < 832) {                // stage 9: -pi*(q*64+lane)/256, q=0..3
        ang = -3.14159265358979f * (float)(t - 576) * (1.f / 256.f);
      } else {                             // unpack: -pi*k/512, k=r*64+lane
        ang = -3.14159265358979f * (float)(t - 832) * (1.f / 512.f);
      }
      float c = __cosf(ang), sn = __sinf(ang);
      if (neg) { c = -c; sn = -sn; }
      twtab[t] = make_float2(c, sn);
    }
  }
  __threadfence();
  cg::this_grid().sync();

  // ---- Phase B: grid-stride prep (old k_prep, 11264 jobs) ----
  for (int b = blockIdx.x; b < 11264; b += (int)gridDim.x) {
    if (b < 8192) {
      int i = b * 256 + tid;
      float4 v = ((const float4*)x)[i];
      ushort4 o;
      o.x = f2bf(v.x); o.y = f2bf(v.y); o.z = f2bf(v.z); o.w = f2bf(v.w);
      ((ushort4*)xb)[i] = o;
    } else if (b < 9216) {
      int i = (b - 8192) * 256 + tid;
      float4 v = ((const float4*)pw)[i];
      ushort4 o;
      o.x = f2bf(v.x); o.y = f2bf(v.y); o.z = f2bf(v.z); o.w = f2bf(v.w);
      ((ushort4*)pwb)[i] = o;
    } else if (b < 10240) {
      int i = (b - 9216) * 256 + tid;
      float4 v = ((const float4*)dw)[i];
      ushort4 o;
      o.x = f2bf(v.x); o.y = f2bf(v.y); o.z = f2bf(v.z); o.w = f2bf(v.w);
      ((ushort4*)dwb)[i] = o;
    } else {
      int idx = (b - 10240) * 256 + tid;    // 262144 ushort4's
      int n = idx >> 8;
      int k0 = (idx & 255) * 4;
      ushort4 o;
      o.x = f2bf(s[(k0 + 0 - n) & 1023]);
      o.y = f2bf(s[(k0 + 1 - n) & 1023]);
      o.z = f2bf(s[(k0 + 2 - n) & 1023]);
      o.w = f2bf(s[(k0 + 3 - n) & 1023]);
      ((ushort4*)Sb)[idx] = o;
    }
  }
}

// ============ counted-vmcnt double-buffered GEMM plumbing ============
#define GB_BARRIER asm volatile("s_barrier" ::: "memory")
#define GB_WAITV(N) asm volatile("s_waitcnt vmcnt(" #N ")" ::: "memory")

// ---------------- GEMM1 128x128 tiles (512, XCD-swizzled) + W2 64x64 tiles (256, tail) ----------
__global__ __launch_bounds__(256, 2) void k_gemm1w2(const unsigned short* __restrict__ xb,
                                                    const unsigned short* __restrict__ pwb,
                                                    const unsigned short* __restrict__ dwb,
                                                    const unsigned short* __restrict__ Sb,
                                                    unsigned short* __restrict__ comp,
                                                    unsigned short* __restrict__ W2) {
  __shared__ __align__(16) unsigned short As[2][128 * 64];   // 32 KB
  __shared__ __align__(16) unsigned short Bs[2][128 * 64];   // 32 KB
  const int tid = threadIdx.x;
  const int lane = tid & 63;
  const int wave = tid >> 6;
  const int mrow = lane & 15;
  const int kq = lane >> 4;
  const int sw = mrow & 7;
  const int ar = tid >> 3;
  const int ac = (((tid & 7) ^ (ar & 7))) * 8;

  if (blockIdx.x < 512) {
    // ---- GEMM1: comp = silu(xb @ pwb^T), 128x128 tile ----
    const int xcd = blockIdx.x & 7;
    const int j = blockIdx.x >> 3;          // 0..63
    const int ntile = j & 7;                // 8 n-tiles of 128 share one A-tile per xcd
    const int bmIdx = xcd + 8 * (j >> 3);   // 0..63
    const int bm = bmIdx * 128;
    const int bn = ntile * 128;
    const int mhalf = (wave & 1) * 64;
    const int nhalf = (wave >> 1) * 64;
    f32x4 acc[4][4] = {};
    const unsigned short* Abase = xb + (size_t)(bm + ar) * 1024 + ac;
    const unsigned short* Bbase = pwb + (size_t)(bn + ar) * 1024 + ac;

#define G1_STAGE(KT, BUF)                                                                     \
    { const int k0_ = (KT) * 64;                                                              \
      _Pragma("unroll")                                                                       \
      for (int r = 0; r < 4; ++r) {                                                           \
        __builtin_amdgcn_global_load_lds(                                                     \
            (const __attribute__((address_space(1))) void*)(Abase + (size_t)(r * 32) * 1024 + k0_), \
            (__attribute__((address_space(3))) void*)((char*)As[BUF] + r * 4096 + wave * 1024), 16, 0, 0); \
        __builtin_amdgcn_global_load_lds(                                                     \
            (const __attribute__((address_space(1))) void*)(Bbase + (size_t)(r * 32) * 1024 + k0_), \
            (__attribute__((address_space(3))) void*)((char*)Bs[BUF] + r * 4096 + wave * 1024), 16, 0, 0); } }

#define G1_COMP(BUF)                                                                          \
    { const char* AsB = (const char*)As[BUF];                                                 \
      const char* BsB = (const char*)Bs[BUF];                                                 \
      _Pragma("unroll")                                                                       \
      for (int kc = 0; kc < 2; ++kc) {                                                        \
        const int chunk = (kc << 2) | kq;                                                     \
        bf16x8 af[4], bfr[4];                                                                 \
        _Pragma("unroll")                                                                     \
        for (int mt = 0; mt < 4; ++mt)                                                        \
          af[mt] = *(const bf16x8*)(AsB + (mhalf + mt * 16 + mrow) * 128 + ((chunk ^ sw) << 4)); \
        _Pragma("unroll")                                                                     \
        for (int nt = 0; nt < 4; ++nt)                                                        \
          bfr[nt] = *(const bf16x8*)(BsB + (nhalf + nt * 16 + mrow) * 128 + ((chunk ^ sw) << 4)); \
        _Pragma("unroll")                                                                     \
        for (int mt = 0; mt < 4; ++mt)                                                        \
          _Pragma("unroll")                                                                   \
          for (int nt = 0; nt < 4; ++nt)                                                      \
            acc[mt][nt] = __builtin_amdgcn_mfma_f32_16x16x32_bf16(af[mt], bfr[nt], acc[mt][nt], 0, 0, 0); } }

    G1_STAGE(0, 0);
    #pragma unroll 1
    for (int kt = 0; kt < 14; kt += 2) {
      G1_STAGE(kt + 1, 1); GB_WAITV(8); GB_BARRIER; G1_COMP(0); GB_BARRIER;
      G1_STAGE(kt + 2, 0); GB_WAITV(8); GB_BARRIER; G1_COMP(1); GB_BARRIER;
    }
    G1_STAGE(15, 1); GB_WAITV(8); GB_BARRIER; G1_COMP(0); GB_BARRIER;
    GB_WAITV(0); GB_BARRIER; G1_COMP(1);

    const int col = bn + nhalf + (lane & 15);
    const int rbase = bm + mhalf + (lane >> 4) * 4;
    #pragma unroll
    for (int mt = 0; mt < 4; ++mt)
      #pragma unroll
      for (int r = 0; r < 4; ++r) {
        const int row = rbase + mt * 16 + r;
        #pragma unroll
        for (int nt = 0; nt < 4; ++nt) {
          float v = acc[mt][nt][r];
          comp[(size_t)row * 1024 + (col + nt * 16)] = f2bf(v / (1.f + expf(-v)));
        }
      }
    return;
  }

  // ---- W2 = dwb @ Sb^T, 64x64 tile ----
  const int wbid = blockIdx.x - 512;      // 0..255
  const int bm = (wbid >> 4) * 64;
  const int bn = (wbid & 15) * 64;
  const int wm = wave & 1;
  const int wn = wave >> 1;
  f32x4 acc[2][2] = {};
  const unsigned short* Abase = dwb + (size_t)(bm + ar) * 1024 + ac;
  const unsigned short* Bbase = Sb + (size_t)(bn + ar) * 1024 + ac;

#define W2_STAGE(KT, BUF)                                                                     \
  { const int k0_ = (KT) * 64;                                                                \
    _Pragma("unroll")                                                                         \
    for (int r = 0; r < 2; ++r) {                                                             \
      __builtin_amdgcn_global_load_lds(                                                       \
          (const __attribute__((address_space(1))) void*)(Abase + (size_t)(r * 32) * 1024 + k0_), \
          (__attribute__((address_space(3))) void*)((char*)As[BUF] + r * 4096 + wave * 1024), 16, 0, 0); \
      __builtin_amdgcn_global_load_lds(                                                       \
          (const __attribute__((address_space(1))) void*)(Bbase + (size_t)(r * 32) * 1024 + k0_), \
          (__attribute__((address_space(3))) void*)((char*)Bs[BUF] + r * 4096 + wave * 1024), 16, 0, 0); } }

#define W2_COMP(BUF)                                                                          \
  { const char* AsB = (const char*)As[BUF];                                                   \
    const char* BsB = (const char*)Bs[BUF];                                                   \
    _Pragma("unroll")                                                                         \
    for (int kc = 0; kc < 2; ++kc) {                                                          \
      const int chunk = (kc << 2) | kq;                                                       \
      bf16x8 af[2], bfr[2];                                                                   \
      _Pragma("unroll")                                                                       \
      for (int mt = 0; mt < 2; ++mt)                                                          \
        af[mt] = *(const bf16x8*)(AsB + (wm * 32 + mt * 16 + mrow) * 128 + ((chunk ^ sw) << 4)); \
      _Pragma("unroll")                                                                       \
      for (int nt = 0; nt < 2; ++nt)                                                          \
        bfr[nt] = *(const bf16x8*)(BsB + (wn * 32 + nt * 16 + mrow) * 128 + ((chunk ^ sw) << 4)); \
      _Pragma("unroll")                                                                       \
      for (int mt = 0; mt < 2; ++mt)                                                          \
        _Pragma("unroll")                                                                     \
        for (int nt = 0; nt < 2; ++nt)                                                        \
          acc[mt][nt] = __builtin_amdgcn_mfma_f32_16x16x32_bf16(af[mt], bfr[nt], acc[mt][nt], 0, 0, 0); } }

  W2_STAGE(0, 0);
  #pragma unroll 1
  for (int kt = 0; kt < 14; kt += 2) {
    W2_STAGE(kt + 1, 1); GB_WAITV(4); GB_BARRIER; W2_COMP(0); GB_BARRIER;
    W2_STAGE(kt + 2, 0); GB_WAITV(4); GB_BARRIER; W2_COMP(1); GB_BARRIER;
  }
  W2_STAGE(15, 1); GB_WAITV(4); GB_BARRIER; W2_COMP(0); GB_BARRIER;
  GB_WAITV(0); GB_BARRIER; W2_COMP(1);

  const int col = bn + wn * 32 + (lane & 15);
  const int rbase = bm + wm * 32 + (lane >> 4) * 4;
  #pragma unroll
  for (int mt = 0; mt < 2; ++mt)
    #pragma unroll
    for (int nt = 0; nt < 2; ++nt)
      #pragma unroll
      for (int r = 0; r < 4; ++r) {
        int row = rbase + mt * 16 + r;
        W2[(size_t)row * 1024 + (col + nt * 16)] = f2bf(acc[mt][nt][r]);
      }
}

// ---------------- fused LayerNorm + Parseval u2, TWO rows per wave, table twiddles ----------------
#define BFLY2(ZR, ZI, I, J, C, S)                              \
  {                                                            \
    float tr_ = ZR[J] * (C) - ZI[J] * (S);                     \
    float ti_ = ZR[J] * (S) + ZI[J] * (C);                     \
    ZR[J] = ZR[I] - tr_; ZI[J] = ZI[I] - ti_;                  \
    ZR[I] += tr_;        ZI[I] += ti_;                         \
  }

__global__ __launch_bounds__(256) void k_ln(unsigned short* __restrict__ comp,
                                            const float* __restrict__ ln_g,
                                            const float* __restrict__ ln_b,
                                            const float* __restrict__ pw_par,
                                            const float2* __restrict__ twtab,
                                            float* __restrict__ u2) {
  const int tid = threadIdx.x;
  const int lane = tid & 63;
  const int wv = tid >> 6;
  const int rowA = blockIdx.x * 8 + wv * 2;      // this wave: rows rowA, rowA+1
  const int rowB = rowA + 1;
  const size_t offA = (size_t)rowA * 1024;
  const size_t offB = (size_t)rowB * 1024;
  const int bl = __brev((unsigned)lane) >> 26;   // brev6(lane)
  const int ybase = bl * 16;

  const u16x8* srcA = (const u16x8*)(comp + offA + ybase);
  const u16x8* srcB = (const u16x8*)(comp + offB + ybase);
  u16x8 a0A = srcA[0], a1A = srcA[1];
  u16x8 a0B = srcB[0], a1B = srcB[1];

  // table twiddles (coalesced float2 loads, L2-hot; overlap with LN below)
  float2 tws[6];
  #pragma unroll
  for (int st = 0; st < 6; ++st) tws[st] = twtab[st * 64 + lane];
  float2 tw7 = twtab[384 + lane];
  float2 tw8a = twtab[448 + lane], tw8b = twtab[512 + lane];
  float2 tw9a = twtab[576 + lane], tw9b = twtab[640 + lane];
  float2 tw9c = twtab[704 + lane], tw9d = twtab[768 + lane];

  float yA[16], yB[16];
  #pragma unroll
  for (int i = 0; i < 8; ++i) {
    yA[i] = bf2f(a0A[i]); yA[8 + i] = bf2f(a1A[i]);
    yB[i] = bf2f(a0B[i]); yB[8 + i] = bf2f(a1B[i]);
  }

  // LayerNorm (two-pass, wave-shfl reductions, both rows interleaved)
  float s1A = 0.f, s1B = 0.f;
  #pragma unroll
  for (int i = 0; i < 16; ++i) { s1A += yA[i]; s1B += yB[i]; }
  #pragma unroll
  for (int o = 32; o; o >>= 1) { s1A += __shfl_xor(s1A, o); s1B += __shfl_xor(s1B, o); }
  const float muA = s1A * (1.f / 1024.f);
  const float muB = s1B * (1.f / 1024.f);
  float s2A = 0.f, s2B = 0.f;
  #pragma unroll
  for (int i = 0; i < 16; ++i) {
    float dA = yA[i] - muA; s2A += dA * dA;
    float dB = yB[i] - muB; s2B += dB * dB;
  }
  #pragma unroll
  for (int o = 32; o; o >>= 1) { s2A += __shfl_xor(s2A, o); s2B += __shfl_xor(s2B, o); }
  const float invA = rsqrtf(s2A * (1.f / 1024.f) + 1e-5f);
  const float invB = rsqrtf(s2B * (1.f / 1024.f) + 1e-5f);

  const float4* gp = (const float4*)(ln_g + ybase);
  const float4* bp = (const float4*)(ln_b + ybase);
  #pragma unroll
  for (int q = 0; q < 4; ++q) {
    float4 g = gp[q], b = bp[q];
    yA[4 * q + 0] = (yA[4 * q + 0] - muA) * invA * g.x + b.x;
    yA[4 * q + 1] = (yA[4 * q + 1] - muA) * invA * g.y + b.y;
    yA[4 * q + 2] = (yA[4 * q + 2] - muA) * invA * g.z + b.z;
    yA[4 * q + 3] = (yA[4 * q + 3] - muA) * invA * g.w + b.w;
    yB[4 * q + 0] = (yB[4 * q + 0] - muB) * invB * g.x + b.x;
    yB[4 * q + 1] = (yB[4 * q + 1] - muB) * invB * g.y + b.y;
    yB[4 * q + 2] = (yB[4 * q + 2] - muB) * invB * g.z + b.z;
    yB[4 * q + 3] = (yB[4 * q + 3] - muB) * invB * g.w + b.w;
  }
  {
    u16x8 o0A, o1A, o0B, o1B;
    #pragma unroll
    for (int i = 0; i < 8; ++i) {
      o0A[i] = f2bf(yA[i]); o1A[i] = f2bf(yA[8 + i]);
      o0B[i] = f2bf(yB[i]); o1B[i] = f2bf(yB[8 + i]);
    }
    u16x8* dstA = (u16x8*)(comp + offA + ybase);
    u16x8* dstB = (u16x8*)(comp + offB + ybase);
    dstA[0] = o0A; dstA[1] = o1A;
    dstB[0] = o0B; dstB[1] = o1B;
  }

  // pack: position p=r*64+lane holds z = (y[2c], y[2c+1]), c=brev3(r)
  float zrA[8], ziA[8], zrB[8], ziB[8];
  const int cmap[8] = {0, 4, 2, 6, 1, 5, 3, 7};   // brev3
  #pragma unroll
  for (int r = 0; r < 8; ++r) {
    zrA[r] = yA[2 * cmap[r]]; ziA[r] = yA[2 * cmap[r] + 1];
    zrB[r] = yB[2 * cmap[r]]; ziB[r] = yB[2 * cmap[r] + 1];
  }

  // stages s=1..6: partner = lane ^ 2^(s-1); batched shfls + table twiddles (sign pre-folded).
  #pragma unroll
  for (int s = 1; s <= 6; ++s) {
    const int half = 1 << (s - 1);
    const float cs = tws[s - 1].x;
    const float ss = tws[s - 1].y;
    const bool hi = (lane & half) != 0;
    float prA[8], piA[8], prB[8], piB[8];
    #pragma unroll
    for (int r = 0; r < 8; ++r) {
      prA[r] = __shfl_xor(zrA[r], half); piA[r] = __shfl_xor(ziA[r], half);
      prB[r] = __shfl_xor(zrB[r], half); piB[r] = __shfl_xor(ziB[r], half);
    }
    #pragma unroll
    for (int r = 0; r < 8; ++r) {
      {
        const float br = hi ? prA[r] : zrA[r];
        const float bi = hi ? piA[r] : ziA[r];
        const float vr = hi ? zrA[r] : prA[r];
        const float vi = hi ? ziA[r] : piA[r];
        zrA[r] = br + cs * vr - ss * vi;
        ziA[r] = bi + cs * vi + ss * vr;
      }
      {
        const float br = hi ? prB[r] : zrB[r];
        const float bi = hi ? piB[r] : ziB[r];
        const float vr = hi ? zrB[r] : prB[r];
        const float vi = hi ? ziB[r] : piB[r];
        zrB[r] = br + cs * vr - ss * vi;
        ziB[r] = bi + cs * vi + ss * vr;
      }
    }
  }
  // stage s=7 (half=64): pairs (r, r^1), pos = lane
  {
    const float c = tw7.x, sn = tw7.y;
    BFLY2(zrA, ziA, 0, 1, c, sn); BFLY2(zrA, ziA, 2, 3, c, sn);
    BFLY2(zrA, ziA, 4, 5, c, sn); BFLY2(zrA, ziA, 6, 7, c, sn);
    BFLY2(zrB, ziB, 0, 1, c, sn); BFLY2(zrB, ziB, 2, 3, c, sn);
    BFLY2(zrB, ziB, 4, 5, c, sn); BFLY2(zrB, ziB, 6, 7, c, sn);
  }
  // stage s=8 (half=128): pairs (r, r^2), pos = (r&1)*64 + lane
  {
    const float ca = tw8a.x, sa = tw8a.y;
    const float cb = tw8b.x, sb = tw8b.y;
    BFLY2(zrA, ziA, 0, 2, ca, sa); BFLY2(zrA, ziA, 4, 6, ca, sa);
    BFLY2(zrA, ziA, 1, 3, cb, sb); BFLY2(zrA, ziA, 5, 7, cb, sb);
    BFLY2(zrB, ziB, 0, 2, ca, sa); BFLY2(zrB, ziB, 4, 6, ca, sa);
    BFLY2(zrB, ziB, 1, 3, cb, sb); BFLY2(zrB, ziB, 5, 7, cb, sb);
  }
  // stage s=9 (half=256): pairs (r, r^4), pos = (r&3)*64 + lane
  {
    const float ca = tw9a.x, sa = tw9a.y;
    const float cb = tw9b.x, sb = tw9b.y;
    const float cc = tw9c.x, sc = tw9c.y;
    const float cd = tw9d.x, sd = tw9d.y;
    BFLY2(zrA, ziA, 0, 4, ca, sa); BFLY2(zrA, ziA, 1, 5, cb, sb);
    BFLY2(zrA, ziA, 2, 6, cc, sc); BFLY2(zrA, ziA, 3, 7, cd, sd);
    BFLY2(zrB, ziB, 0, 4, ca, sa); BFLY2(zrB, ziB, 1, 5, cb, sb);
    BFLY2(zrB, ziB, 2, 6, cc, sc); BFLY2(zrB, ziB, 3, 7, cd, sd);
  }

  // unpack real spectrum (Z_k at r=k>>6, lane=k&63) + Parseval; mirrors batched; table trig.
  float2 twu[8];
  #pragma unroll
  for (int r = 0; r < 8; ++r) twu[r] = twtab[832 + r * 64 + lane];
  const int srcl = (64 - lane) & 63;
  float mrA[8], miA[8], mrB[8], miB[8];
  #pragma unroll
  for (int r = 0; r < 8; ++r) {
    mrA[r] = __shfl(zrA[7 - r], srcl); miA[r] = __shfl(ziA[7 - r], srcl);
    mrB[r] = __shfl(zrB[7 - r], srcl); miB[r] = __shfl(ziB[7 - r], srcl);
  }
  if (lane == 0) {
    #pragma unroll
    for (int r = 0; r < 8; ++r) {
      mrA[r] = zrA[(8 - r) & 7]; miA[r] = ziA[(8 - r) & 7];
      mrB[r] = zrB[(8 - r) & 7]; miB[r] = ziB[(8 - r) & 7];
    }
  }
  float pA = 0.f, pB = 0.f;
  #pragma unroll
  for (int r = 0; r < 8; ++r) {
    const int k = r * 64 + lane;
    const float c = twu[r].x, sn = twu[r].y;
    const float w = pw_par[k];
    {
      const float er = 0.5f * (zrA[r] + mrA[r]);
      const float ei = 0.5f * (ziA[r] - miA[r]);
      const float orr = 0.5f * (ziA[r] + miA[r]);
      const float oi = -0.5f * (zrA[r] - mrA[r]);
      const float xr = er + orr * c - oi * sn;
      const float xi = ei + orr * sn + oi * c;
      pA += w * (xr * xr + xi * xi);
    }
    {
      const float er = 0.5f * (zrB[r] + mrB[r]);
      const float ei = 0.5f * (ziB[r] - miB[r]);
      const float orr = 0.5f * (ziB[r] + miB[r]);
      const float oi = -0.5f * (zrB[r] - mrB[r]);
      const float xr = er + orr * c - oi * sn;
      const float xi = ei + orr * sn + oi * c;
      pB += w * (xr * xr + xi * xi);
    }
  }
  if (lane == 0) {
    const float w512 = pw_par[512];
    const float xA = zrA[0] - ziA[0];
    const float xB = zrB[0] - ziB[0];
    pA += w512 * xA * xA;
    pB += w512 * xB * xB;
  }
  #pragma unroll
  for (int o = 32; o; o >>= 1) { pA += __shfl_xor(pA, o); pB += __shfl_xor(pB, o); }
  if (lane == 0) { u2[rowA] = pA; u2[rowB] = pB; }
}

__device__ __forceinline__ float gamma_from_u2(float U2, float tv) {
  const float sc = 0.01f;      // sqrt(1e-4)
  const float c = 1e-4f;
  float nrm = sqrtf(U2);
  float nu = fmaxf(nrm, 1e-7f);
  float su = fminf(fmaxf(sc * nu, 1e-7f), 1.f - 1e-5f);
  float Af = tanhf((1.f - tv) * atanhf(su)) / (sc * nu);
  float nvn = fmaxf(fabsf(tv) * nrm, 1e-7f);
  float svv = fminf(fmaxf(sc * nvn, 1e-7f), 1.f - 1e-5f);
  float Bf = tv * tanhf(tv * atanhf(svv)) / (sc * nvn);
  float x2s = Af * Af * U2, y2s = Bf * Bf * U2, xys = Af * Bf * U2;
  float numc = (1.f + 2.f * c * xys + c * y2s) * Af + (1.f - c * x2s) * Bf;
  float den = fmaxf(1.f + 2.f * c * xys + c * c * x2s * y2s, 1e-7f);
  return numc / den;
}

// ---------------- GEMM3: out = gamma(u2[row]) * scale * (comp @ W2^T), fp32 out ----------------
// grid 512 (XCD-swizzled); dbuf LDS 64KB -> 2 blocks/CU.
__global__ __launch_bounds__(256, 2) void k_gemm23(const unsigned short* __restrict__ comp,
                                                   const unsigned short* __restrict__ W2,
                                                   const float* __restrict__ u2,
                                                   const float* __restrict__ t_ptr,
                                                   const float* __restrict__ scale_ptr,
                                                   float* __restrict__ out) {
  __shared__ __align__(16) unsigned short As[2][128 * 64];   // 32 KB
  __shared__ __align__(16) unsigned short Bs[2][128 * 64];   // 32 KB
  __shared__ float gs[128];
  const int tid = threadIdx.x;
  const int lane = tid & 63;
  const int wave = tid >> 6;
  const int xcd = blockIdx.x & 7;
  const int j = blockIdx.x >> 3;          // 0..63
  const int ntile = j & 7;                // 8 n-tiles of 128 share one A-tile per xcd
  const int bmIdx = xcd + 8 * (j >> 3);   // 0..63
  const int bm = bmIdx * 128;
  const int bn = ntile * 128;
  const int mrow = lane & 15;
  const int kq = lane >> 4;
  const int sw = mrow & 7;
  const int mhalf = (wave & 1) * 64;
  const int nhalf = (wave >> 1) * 64;
  const int ar = tid >> 3;
  const int ac = (((tid & 7) ^ (ar & 7))) * 8;
  const unsigned short* Abase = comp + (size_t)(bm + ar) * 1024 + ac;
  const unsigned short* Bbase = W2 + (size_t)(bn + ar) * 1024 + ac;

  // per-row gamma*scale for this block's 128 rows (u2 ready from k_ln);
  // ds_write retires with the first compute's lgkm waits; read only in epilogue.
  if (tid < 128) gs[tid] = gamma_from_u2(u2[bm + tid], t_ptr[0]) * scale_ptr[0];

  f32x4 acc[4][4] = {};

#define G3_STAGE(KT, BUF)                                                                     \
  { const int k0_ = (KT) * 64;                                                                \
    _Pragma("unroll")                                                                         \
    for (int r = 0; r < 4; ++r) {                                                             \
      __builtin_amdgcn_global_load_lds(                                                       \
          (const __attribute__((address_space(1))) void*)(Abase + (size_t)(r * 32) * 1024 + k0_), \
          (__attribute__((address_space(3))) void*)((char*)As[BUF] + r * 4096 + wave * 1024), 16, 0, 0); \
      __builtin_amdgcn_global_load_lds(                                                       \
          (const __attribute__((address_space(1))) void*)(Bbase + (size_t)(r * 32) * 1024 + k0_), \
          (__attribute__((address_space(3))) void*)((char*)Bs[BUF] + r * 4096 + wave * 1024), 16, 0, 0); } }

#define G3_COMP(BUF)                                                                          \
  { const char* AsB = (const char*)As[BUF];                                                   \
    const char* BsB = (const char*)Bs[BUF];                                                   \
    _Pragma("unroll")                                                                         \
    for (int kc = 0; kc < 2; ++kc) {                                                          \
      const int chunk = (kc << 2) | kq;                                                       \
      bf16x8 af[4], bfr[4];                                                                   \
      _Pragma("unroll")                                                                       \
      for (int mt = 0; mt < 4; ++mt)                                                          \
        af[mt] = *(const bf16x8*)(AsB + (mhalf + mt * 16 + mrow) * 128 + ((chunk ^ sw) << 4)); \
      _Pragma("unroll")                                                                       \
      for (int nt = 0; nt < 4; ++nt)                                                          \
        bfr[nt] = *(const bf16x8*)(BsB + (nhalf + nt * 16 + mrow) * 128 + ((chunk ^ sw) << 4)); \
      _Pragma("unroll")                                                                       \
      for (int mt = 0; mt < 4; ++mt)                                                          \
        _Pragma("unroll")                                                                     \
        for (int nt = 0; nt < 4; ++nt)                                                        \
          acc[mt][nt] = __builtin_amdgcn_mfma_f32_16x16x32_bf16(af[mt], bfr[nt], acc[mt][nt], 0, 0, 0); } }

  G3_STAGE(0, 0);
  #pragma unroll 1
  for (int kt = 0; kt < 14; kt += 2) {
    G3_STAGE(kt + 1, 1); GB_WAITV(8); GB_BARRIER; G3_COMP(0); GB_BARRIER;
    G3_STAGE(kt + 2, 0); GB_WAITV(8); GB_BARRIER; G3_COMP(1); GB_BARRIER;
  }
  G3_STAGE(15, 1); GB_WAITV(8); GB_BARRIER; G3_COMP(0); GB_BARRIER;
  GB_WAITV(0); GB_BARRIER; G3_COMP(1);

  const int col = bn + (wave >> 1) * 64 + (lane & 15);
  const int rbase = bm + (wave & 1) * 64 + (lane >> 4) * 4;
  #pragma unroll
  for (int mt = 0; mt < 4; ++mt)
    #pragma unroll
    for (int r = 0; r < 4; ++r) {
      const int row = rbase + mt * 16 + r;
      const float gsc = gs[row - bm];
      #pragma unroll
      for (int nt = 0; nt < 4; ++nt)
        out[(size_t)row * 1024 + (col + nt * 16)] = acc[mt][nt][r] * gsc;
    }
}

extern "C" void kernel_launch(void* const* d_in, const int* in_sizes, int n_in,
                              void* d_out, int out_size, void* d_ws, size_t ws_size,
                              hipStream_t stream) {
  const float* x      = (const float*)d_in[0];
  const float* proj_w = (const float*)d_in[1];
  const float* ln_g   = (const float*)d_in[2];
  const float* ln_b   = (const float*)d_in[3];
  const float* freq_w = (const float*)d_in[4];
  const float* t_p    = (const float*)d_in[5];
  const float* down_w = (const float*)d_in[6];
  const float* scale  = (const float*)d_in[7];

  char* ws = (char*)d_ws;
  unsigned short* xb   = (unsigned short*)ws;                 // 16 MB
  unsigned short* pwb  = (unsigned short*)(ws + (16u << 20)); // 2 MB
  unsigned short* dwb  = (unsigned short*)(ws + (18u << 20)); // 2 MB
  unsigned short* comp = (unsigned short*)(ws + (20u << 20)); // 16 MB
  unsigned short* Sb   = (unsigned short*)(ws + (36u << 20)); // 2 MB
  unsigned short* W2   = (unsigned short*)(ws + (38u << 20)); // 2 MB
  float* s_buf         = (float*)(ws + (40u << 20));          // 4 KB
  float* pw_par        = (float*)(ws + (40u << 20) + 4096);   // ~2 KB
  float* u2            = (float*)(ws + (40u << 20) + 8192);   // 32 KB
  float2* twtab        = (float2*)(ws + (40u << 20) + 8192 + 32768);  // ~11 KB

  void* args[] = {(void*)&freq_w, (void*)&x, (void*)&proj_w, (void*)&down_w,
                  (void*)&s_buf, (void*)&pw_par, (void*)&twtab,
                  (void*)&xb, (void*)&pwb, (void*)&dwb, (void*)&Sb};
  hipLaunchCooperativeKernel((void*)k_sprep, dim3(1024), dim3(256), args, 0, stream);
  k_gemm1w2<<<768, 256, 0, stream>>>(xb, pwb, dwb, Sb, comp, W2);
  k_ln<<<1024, 256, 0, stream>>>(comp, ln_g, ln_b, pw_par, twtab, u2);
  k_gemm23<<<512, 256, 0, stream>>>(comp, W2, u2, t_p, scale, (float*)d_out);
}

// Round 12
// 174.722 us; speedup vs baseline: 2.1062x; 2.1062x over previous
//
#include <hip/hip_runtime.h>
#include <math.h>

typedef float f32x4 __attribute__((ext_vector_type(4)));
typedef __bf16 bf16x8 __attribute__((ext_vector_type(8)));
typedef unsigned short u16x8 __attribute__((ext_vector_type(8)));

__device__ __forceinline__ unsigned short f2bf(float f) {
  unsigned u = __float_as_uint(f);
  unsigned r = (u + 0x7fffu + ((u >> 16) & 1u)) >> 16;
  return (unsigned short)r;
}
__device__ __forceinline__ float bf2f(unsigned short h) {
  return __uint_as_float(((unsigned)h) << 16);
}

// ---------------- block reduction helper ----------------
__device__ __forceinline__ float blk_sum(float v, float* red, int tid) {
  #pragma unroll
  for (int o = 32; o; o >>= 1) v += __shfl_down(v, o);
  __syncthreads();
  if ((tid & 63) == 0) red[tid >> 6] = v;
  __syncthreads();
  return red[0] + red[1] + red[2] + red[3];
}

// ---------------- softmax(freq_w) + s = irfft(softmax) + Parseval weights ----------------
__global__ __launch_bounds__(256) void k_s(const float* __restrict__ fw,
                                           float* __restrict__ s,
                                           float* __restrict__ pw) {
  __shared__ float wsh[513];
  __shared__ float red[4];
  int tid = threadIdx.x;
  float m = -1e30f;
  for (int i = tid; i < 513; i += 256) m = fmaxf(m, fw[i]);
  #pragma unroll
  for (int o = 32; o; o >>= 1) m = fmaxf(m, __shfl_down(m, o));
  if ((tid & 63) == 0) red[tid >> 6] = m;
  __syncthreads();
  m = fmaxf(fmaxf(red[0], red[1]), fmaxf(red[2], red[3]));
  float sum = 0.f;
  for (int i = tid; i < 513; i += 256) {
    float e = expf(fw[i] - m);
    wsh[i] = e;
    sum += e;
  }
  sum = blk_sum(sum, red, tid);   // syncs inside -> wsh visible after
  float inv = 1.f / sum;

  // Parseval weights: pw[f] = c_f * wnorm_f^2 / 1024, c = 1,2,...,2,1
  if (blockIdx.x == 0) {
    for (int i = tid; i < 513; i += 256) {
      float wn = wsh[i] * inv;
      float cf = (i == 0 || i == 512) ? 1.f : 2.f;
      pw[i] = cf * wn * wn * (1.f / 1024.f);
    }
  }

  int gid = blockIdx.x * 256 + tid;   // 8192 threads: d = gid>>3, chunk = gid&7
  int d = gid >> 3;
  int chunk = gid & 7;
  float acc = 0.f;
  for (int f = 1 + chunk; f < 512; f += 8) {
    int p = (f * d) & 1023;
    acc += wsh[f] * __cosf(6.283185307179586f * (float)p * (1.f / 1024.f));
  }
  acc += __shfl_xor(acc, 1);
  acc += __shfl_xor(acc, 2);
  acc += __shfl_xor(acc, 4);
  if (chunk == 0) {
    float tot = wsh[0] + ((d & 1) ? -wsh[512] : wsh[512]) + 2.f * acc;
    s[d] = tot * inv * (1.f / 1024.f);
  }
}

// ---------------- prep: cvt x, cvt proj_w, cvt down_w, fill circulant Sb, fill twiddle table ----
// grid 11270: [0,8192) cvt x; [8192,9216) pw; [9216,10240) dw; [10240,11264) Sb;
// [11264,11270) twiddle table (1344 float2, verified on HW in R11 — bit-identical absmax).
__global__ __launch_bounds__(256) void k_prep(const float* __restrict__ x,
                                              const float* __restrict__ pw,
                                              const float* __restrict__ dw,
                                              const float* __restrict__ s,
                                              unsigned short* __restrict__ xb,
                                              unsigned short* __restrict__ pwb,
                                              unsigned short* __restrict__ dwb,
                                              unsigned short* __restrict__ Sb,
                                              float2* __restrict__ twtab) {
  int b = blockIdx.x;
  int tid = threadIdx.x;
  if (b < 8192) {
    int i = b * 256 + tid;
    float4 v = ((const float4*)x)[i];
    ushort4 o;
    o.x = f2bf(v.x); o.y = f2bf(v.y); o.z = f2bf(v.z); o.w = f2bf(v.w);
    ((ushort4*)xb)[i] = o;
  } else if (b < 9216) {
    int i = (b - 8192) * 256 + tid;
    float4 v = ((const float4*)pw)[i];
    ushort4 o;
    o.x = f2bf(v.x); o.y = f2bf(v.y); o.z = f2bf(v.z); o.w = f2bf(v.w);
    ((ushort4*)pwb)[i] = o;
  } else if (b < 10240) {
    int i = (b - 9216) * 256 + tid;
    float4 v = ((const float4*)dw)[i];
    ushort4 o;
    o.x = f2bf(v.x); o.y = f2bf(v.y); o.z = f2bf(v.z); o.w = f2bf(v.w);
    ((ushort4*)dwb)[i] = o;
  } else if (b < 11264) {
    int idx = (b - 10240) * 256 + tid;    // 262144 ushort4's
    int n = idx >> 8;
    int k0 = (idx & 255) * 4;
    ushort4 o;
    o.x = f2bf(s[(k0 + 0 - n) & 1023]);
    o.y = f2bf(s[(k0 + 1 - n) & 1023]);
    o.z = f2bf(s[(k0 + 2 - n) & 1023]);
    o.w = f2bf(s[(k0 + 3 - n) & 1023]);
    ((ushort4*)Sb)[idx] = o;
  } else {
    // ---- twiddle table: 1344 float2 entries, same __cosf/__sinf as inline version ----
    int t = (b - 11264) * 256 + tid;
    if (t < 1344) {
      float ang;
      bool neg = false;
      if (t < 384) {                       // stages 1..6, pre-sign-folded
        int st = (t >> 6) + 1, l = t & 63;
        int half = 1 << (st - 1);
        int pos = l & (half - 1);
        ang = -3.14159265358979f * (float)pos / (float)half;
        neg = (l & half) != 0;
      } else if (t < 448) {                // stage 7: -pi*lane/64
        ang = -3.14159265358979f * (float)(t - 384) * (1.f / 64.f);
      } else if (t < 512) {                // stage 8a: -pi*lane/128
        ang = -3.14159265358979f * (float)(t - 448) * (1.f / 128.f);
      } else if (t < 576) {                // stage 8b: -pi*(64+lane)/128
        ang = -3.14159265358979f * (float)(64 + (t - 512)) * (1.f / 128.f);
      } else if (t < 832) {                // stage 9: -pi*(q*64+lane)/256, q=0..3
        ang = -3.14159265358979f * (float)(t - 576) * (1.f / 256.f);
      } else {                             // unpack: -pi*k/512, k=r*64+lane
        ang = -3.14159265358979f * (float)(t - 832) * (1.f / 512.f);
      }
      float c = __cosf(ang), sn = __sinf(ang);
      if (neg) { c = -c; sn = -sn; }
      twtab[t] = make_float2(c, sn);
    }
  }
}

// ============ counted-vmcnt double-buffered GEMM plumbing ============
#define GB_BARRIER asm volatile("s_barrier" ::: "memory")
#define GB_WAITV(N) asm volatile("s_waitcnt vmcnt(" #N ")" ::: "memory")

// ---------------- GEMM1 128x128 tiles (512, XCD-swizzled) + W2 64x64 tiles (256, tail) ----------
__global__ __launch_bounds__(256, 2) void k_gemm1w2(const unsigned short* __restrict__ xb,
                                                    const unsigned short* __restrict__ pwb,
                                                    const unsigned short* __restrict__ dwb,
                                                    const unsigned short* __restrict__ Sb,
                                                    unsigned short* __restrict__ comp,
                                                    unsigned short* __restrict__ W2) {
  __shared__ __align__(16) unsigned short As[2][128 * 64];   // 32 KB
  __shared__ __align__(16) unsigned short Bs[2][128 * 64];   // 32 KB
  const int tid = threadIdx.x;
  const int lane = tid & 63;
  const int wave = tid >> 6;
  const int mrow = lane & 15;
  const int kq = lane >> 4;
  const int sw = mrow & 7;
  const int ar = tid >> 3;
  const int ac = (((tid & 7) ^ (ar & 7))) * 8;

  if (blockIdx.x < 512) {
    // ---- GEMM1: comp = silu(xb @ pwb^T), 128x128 tile ----
    const int xcd = blockIdx.x & 7;
    const int j = blockIdx.x >> 3;          // 0..63
    const int ntile = j & 7;                // 8 n-tiles of 128 share one A-tile per xcd
    const int bmIdx = xcd + 8 * (j >> 3);   // 0..63
    const int bm = bmIdx * 128;
    const int bn = ntile * 128;
    const int mhalf = (wave & 1) * 64;
    const int nhalf = (wave >> 1) * 64;
    f32x4 acc[4][4] = {};
    const unsigned short* Abase = xb + (size_t)(bm + ar) * 1024 + ac;
    const unsigned short* Bbase = pwb + (size_t)(bn + ar) * 1024 + ac;

#define G1_STAGE(KT, BUF)                                                                     \
    { const int k0_ = (KT) * 64;                                                              \
      _Pragma("unroll")                                                                       \
      for (int r = 0; r < 4; ++r) {                                                           \
        __builtin_amdgcn_global_load_lds(                                                     \
            (const __attribute__((address_space(1))) void*)(Abase + (size_t)(r * 32) * 1024 + k0_), \
            (__attribute__((address_space(3))) void*)((char*)As[BUF] + r * 4096 + wave * 1024), 16, 0, 0); \
        __builtin_amdgcn_global_load_lds(                                                     \
            (const __attribute__((address_space(1))) void*)(Bbase + (size_t)(r * 32) * 1024 + k0_), \
            (__attribute__((address_space(3))) void*)((char*)Bs[BUF] + r * 4096 + wave * 1024), 16, 0, 0); } }

#define G1_COMP(BUF)                                                                          \
    { const char* AsB = (const char*)As[BUF];                                                 \
      const char* BsB = (const char*)Bs[BUF];                                                 \
      _Pragma("unroll")                                                                       \
      for (int kc = 0; kc < 2; ++kc) {                                                        \
        const int chunk = (kc << 2) | kq;                                                     \
        bf16x8 af[4], bfr[4];                                                                 \
        _Pragma("unroll")                                                                     \
        for (int mt = 0; mt < 4; ++mt)                                                        \
          af[mt] = *(const bf16x8*)(AsB + (mhalf + mt * 16 + mrow) * 128 + ((chunk ^ sw) << 4)); \
        _Pragma("unroll")                                                                     \
        for (int nt = 0; nt < 4; ++nt)                                                        \
          bfr[nt] = *(const bf16x8*)(BsB + (nhalf + nt * 16 + mrow) * 128 + ((chunk ^ sw) << 4)); \
        _Pragma("unroll")                                                                     \
        for (int mt = 0; mt < 4; ++mt)                                                        \
          _Pragma("unroll")                                                                   \
          for (int nt = 0; nt < 4; ++nt)                                                      \
            acc[mt][nt] = __builtin_amdgcn_mfma_f32_16x16x32_bf16(af[mt], bfr[nt], acc[mt][nt], 0, 0, 0); } }

    G1_STAGE(0, 0);
    #pragma unroll 1
    for (int kt = 0; kt < 14; kt += 2) {
      G1_STAGE(kt + 1, 1); GB_WAITV(8); GB_BARRIER; G1_COMP(0); GB_BARRIER;
      G1_STAGE(kt + 2, 0); GB_WAITV(8); GB_BARRIER; G1_COMP(1); GB_BARRIER;
    }
    G1_STAGE(15, 1); GB_WAITV(8); GB_BARRIER; G1_COMP(0); GB_BARRIER;
    GB_WAITV(0); GB_BARRIER; G1_COMP(1);

    const int col = bn + nhalf + (lane & 15);
    const int rbase = bm + mhalf + (lane >> 4) * 4;
    #pragma unroll
    for (int mt = 0; mt < 4; ++mt)
      #pragma unroll
      for (int r = 0; r < 4; ++r) {
        const int row = rbase + mt * 16 + r;
        #pragma unroll
        for (int nt = 0; nt < 4; ++nt) {
          float v = acc[mt][nt][r];
          comp[(size_t)row * 1024 + (col + nt * 16)] = f2bf(v / (1.f + expf(-v)));
        }
      }
    return;
  }

  // ---- W2 = dwb @ Sb^T, 64x64 tile ----
  const int wbid = blockIdx.x - 512;      // 0..255
  const int bm = (wbid >> 4) * 64;
  const int bn = (wbid & 15) * 64;
  const int wm = wave & 1;
  const int wn = wave >> 1;
  f32x4 acc[2][2] = {};
  const unsigned short* Abase = dwb + (size_t)(bm + ar) * 1024 + ac;
  const unsigned short* Bbase = Sb + (size_t)(bn + ar) * 1024 + ac;

#define W2_STAGE(KT, BUF)                                                                     \
  { const int k0_ = (KT) * 64;                                                                \
    _Pragma("unroll")                                                                         \
    for (int r = 0; r < 2; ++r) {                                                             \
      __builtin_amdgcn_global_load_lds(                                                       \
          (const __attribute__((address_space(1))) void*)(Abase + (size_t)(r * 32) * 1024 + k0_), \
          (__attribute__((address_space(3))) void*)((char*)As[BUF] + r * 4096 + wave * 1024), 16, 0, 0); \
      __builtin_amdgcn_global_load_lds(                                                       \
          (const __attribute__((address_space(1))) void*)(Bbase + (size_t)(r * 32) * 1024 + k0_), \
          (__attribute__((address_space(3))) void*)((char*)Bs[BUF] + r * 4096 + wave * 1024), 16, 0, 0); } }

#define W2_COMP(BUF)                                                                          \
  { const char* AsB = (const char*)As[BUF];                                                   \
    const char* BsB = (const char*)Bs[BUF];                                                   \
    _Pragma("unroll")                                                                         \
    for (int kc = 0; kc < 2; ++kc) {                                                          \
      const int chunk = (kc << 2) | kq;                                                       \
      bf16x8 af[2], bfr[2];                                                                   \
      _Pragma("unroll")                                                                       \
      for (int mt = 0; mt < 2; ++mt)                                                          \
        af[mt] = *(const bf16x8*)(AsB + (wm * 32 + mt * 16 + mrow) * 128 + ((chunk ^ sw) << 4)); \
      _Pragma("unroll")                                                                       \
      for (int nt = 0; nt < 2; ++nt)                                                          \
        bfr[nt] = *(const bf16x8*)(BsB + (wn * 32 + nt * 16 + mrow) * 128 + ((chunk ^ sw) << 4)); \
      _Pragma("unroll")                                                                       \
      for (int mt = 0; mt < 2; ++mt)                                                          \
        _Pragma("unroll")                                                                     \
        for (int nt = 0; nt < 2; ++nt)                                                        \
          acc[mt][nt] = __builtin_amdgcn_mfma_f32_16x16x32_bf16(af[mt], bfr[nt], acc[mt][nt], 0, 0, 0); } }

  W2_STAGE(0, 0);
  #pragma unroll 1
  for (int kt = 0; kt < 14; kt += 2) {
    W2_STAGE(kt + 1, 1); GB_WAITV(4); GB_BARRIER; W2_COMP(0); GB_BARRIER;
    W2_STAGE(kt + 2, 0); GB_WAITV(4); GB_BARRIER; W2_COMP(1); GB_BARRIER;
  }
  W2_STAGE(15, 1); GB_WAITV(4); GB_BARRIER; W2_COMP(0); GB_BARRIER;
  GB_WAITV(0); GB_BARRIER; W2_COMP(1);

  const int col = bn + wn * 32 + (lane & 15);
  const int rbase = bm + wm * 32 + (lane >> 4) * 4;
  #pragma unroll
  for (int mt = 0; mt < 2; ++mt)
    #pragma unroll
    for (int nt = 0; nt < 2; ++nt)
      #pragma unroll
      for (int r = 0; r < 4; ++r) {
        int row = rbase + mt * 16 + r;
        W2[(size_t)row * 1024 + (col + nt * 16)] = f2bf(acc[mt][nt][r]);
      }
}

// ---------------- fused LayerNorm + Parseval u2, TWO rows per wave, table twiddles ----------------
#define BFLY2(ZR, ZI, I, J, C, S)                              \
  {                                                            \
    float tr_ = ZR[J] * (C) - ZI[J] * (S);                     \
    float ti_ = ZR[J] * (S) + ZI[J] * (C);                     \
    ZR[J] = ZR[I] - tr_; ZI[J] = ZI[I] - ti_;                  \
    ZR[I] += tr_;        ZI[I] += ti_;                         \
  }

__global__ __launch_bounds__(256) void k_ln(unsigned short* __restrict__ comp,
                                            const float* __restrict__ ln_g,
                                            const float* __restrict__ ln_b,
                                            const float* __restrict__ pw_par,
                                            const float2* __restrict__ twtab,
                                            float* __restrict__ u2) {
  const int tid = threadIdx.x;
  const int lane = tid & 63;
  const int wv = tid >> 6;
  const int rowA = blockIdx.x * 8 + wv * 2;      // this wave: rows rowA, rowA+1
  const int rowB = rowA + 1;
  const size_t offA = (size_t)rowA * 1024;
  const size_t offB = (size_t)rowB * 1024;
  const int bl = __brev((unsigned)lane) >> 26;   // brev6(lane)
  const int ybase = bl * 16;

  const u16x8* srcA = (const u16x8*)(comp + offA + ybase);
  const u16x8* srcB = (const u16x8*)(comp + offB + ybase);
  u16x8 a0A = srcA[0], a1A = srcA[1];
  u16x8 a0B = srcB[0], a1B = srcB[1];

  // table twiddles (coalesced float2 loads, L2-hot; overlap with LN below)
  float2 tws[6];
  #pragma unroll
  for (int st = 0; st < 6; ++st) tws[st] = twtab[st * 64 + lane];
  float2 tw7 = twtab[384 + lane];
  float2 tw8a = twtab[448 + lane], tw8b = twtab[512 + lane];
  float2 tw9a = twtab[576 + lane], tw9b = twtab[640 + lane];
  float2 tw9c = twtab[704 + lane], tw9d = twtab[768 + lane];

  float yA[16], yB[16];
  #pragma unroll
  for (int i = 0; i < 8; ++i) {
    yA[i] = bf2f(a0A[i]); yA[8 + i] = bf2f(a1A[i]);
    yB[i] = bf2f(a0B[i]); yB[8 + i] = bf2f(a1B[i]);
  }

  // LayerNorm (two-pass, wave-shfl reductions, both rows interleaved)
  float s1A = 0.f, s1B = 0.f;
  #pragma unroll
  for (int i = 0; i < 16; ++i) { s1A += yA[i]; s1B += yB[i]; }
  #pragma unroll
  for (int o = 32; o; o >>= 1) { s1A += __shfl_xor(s1A, o); s1B += __shfl_xor(s1B, o); }
  const float muA = s1A * (1.f / 1024.f);
  const float muB = s1B * (1.f / 1024.f);
  float s2A = 0.f, s2B = 0.f;
  #pragma unroll
  for (int i = 0; i < 16; ++i) {
    float dA = yA[i] - muA; s2A += dA * dA;
    float dB = yB[i] - muB; s2B += dB * dB;
  }
  #pragma unroll
  for (int o = 32; o; o >>= 1) { s2A += __shfl_xor(s2A, o); s2B += __shfl_xor(s2B, o); }
  const float invA = rsqrtf(s2A * (1.f / 1024.f) + 1e-5f);
  const float invB = rsqrtf(s2B * (1.f / 1024.f) + 1e-5f);

  const float4* gp = (const float4*)(ln_g + ybase);
  const float4* bp = (const float4*)(ln_b + ybase);
  #pragma unroll
  for (int q = 0; q < 4; ++q) {
    float4 g = gp[q], b = bp[q];
    yA[4 * q + 0] = (yA[4 * q + 0] - muA) * invA * g.x + b.x;
    yA[4 * q + 1] = (yA[4 * q + 1] - muA) * invA * g.y + b.y;
    yA[4 * q + 2] = (yA[4 * q + 2] - muA) * invA * g.z + b.z;
    yA[4 * q + 3] = (yA[4 * q + 3] - muA) * invA * g.w + b.w;
    yB[4 * q + 0] = (yB[4 * q + 0] - muB) * invB * g.x + b.x;
    yB[4 * q + 1] = (yB[4 * q + 1] - muB) * invB * g.y + b.y;
    yB[4 * q + 2] = (yB[4 * q + 2] - muB) * invB * g.z + b.z;
    yB[4 * q + 3] = (yB[4 * q + 3] - muB) * invB * g.w + b.w;
  }
  {
    u16x8 o0A, o1A, o0B, o1B;
    #pragma unroll
    for (int i = 0; i < 8; ++i) {
      o0A[i] = f2bf(yA[i]); o1A[i] = f2bf(yA[8 + i]);
      o0B[i] = f2bf(yB[i]); o1B[i] = f2bf(yB[8 + i]);
    }
    u16x8* dstA = (u16x8*)(comp + offA + ybase);
    u16x8* dstB = (u16x8*)(comp + offB + ybase);
    dstA[0] = o0A; dstA[1] = o1A;
    dstB[0] = o0B; dstB[1] = o1B;
  }

  // pack: position p=r*64+lane holds z = (y[2c], y[2c+1]), c=brev3(r)
  float zrA[8], ziA[8], zrB[8], ziB[8];
  const int cmap[8] = {0, 4, 2, 6, 1, 5, 3, 7};   // brev3
  #pragma unroll
  for (int r = 0; r < 8; ++r) {
    zrA[r] = yA[2 * cmap[r]]; ziA[r] = yA[2 * cmap[r] + 1];
    zrB[r] = yB[2 * cmap[r]]; ziB[r] = yB[2 * cmap[r] + 1];
  }

  // stages s=1..6: partner = lane ^ 2^(s-1); batched shfls + table twiddles (sign pre-folded).
  #pragma unroll
  for (int s = 1; s <= 6; ++s) {
    const int half = 1 << (s - 1);
    const float cs = tws[s - 1].x;
    const float ss = tws[s - 1].y;
    const bool hi = (lane & half) != 0;
    float prA[8], piA[8], prB[8], piB[8];
    #pragma unroll
    for (int r = 0; r < 8; ++r) {
      prA[r] = __shfl_xor(zrA[r], half); piA[r] = __shfl_xor(ziA[r], half);
      prB[r] = __shfl_xor(zrB[r], half); piB[r] = __shfl_xor(ziB[r], half);
    }
    #pragma unroll
    for (int r = 0; r < 8; ++r) {
      {
        const float br = hi ? prA[r] : zrA[r];
        const float bi = hi ? piA[r] : ziA[r];
        const float vr = hi ? zrA[r] : prA[r];
        const float vi = hi ? ziA[r] : piA[r];
        zrA[r] = br + cs * vr - ss * vi;
        ziA[r] = bi + cs * vi + ss * vr;
      }
      {
        const float br = hi ? prB[r] : zrB[r];
        const float bi = hi ? piB[r] : ziB[r];
        const float vr = hi ? zrB[r] : prB[r];
        const float vi = hi ? ziB[r] : piB[r];
        zrB[r] = br + cs * vr - ss * vi;
        ziB[r] = bi + cs * vi + ss * vr;
      }
    }
  }
  // stage s=7 (half=64): pairs (r, r^1), pos = lane
  {
    const float c = tw7.x, sn = tw7.y;
    BFLY2(zrA, ziA, 0, 1, c, sn); BFLY2(zrA, ziA, 2, 3, c, sn);
    BFLY2(zrA, ziA, 4, 5, c, sn); BFLY2(zrA, ziA, 6, 7, c, sn);
    BFLY2(zrB, ziB, 0, 1, c, sn); BFLY2(zrB, ziB, 2, 3, c, sn);
    BFLY2(zrB, ziB, 4, 5, c, sn); BFLY2(zrB, ziB, 6, 7, c, sn);
  }
  // stage s=8 (half=128): pairs (r, r^2), pos = (r&1)*64 + lane
  {
    const float ca = tw8a.x, sa = tw8a.y;
    const float cb = tw8b.x, sb = tw8b.y;
    BFLY2(zrA, ziA, 0, 2, ca, sa); BFLY2(zrA, ziA, 4, 6, ca, sa);
    BFLY2(zrA, ziA, 1, 3, cb, sb); BFLY2(zrA, ziA, 5, 7, cb, sb);
    BFLY2(zrB, ziB, 0, 2, ca, sa); BFLY2(zrB, ziB, 4, 6, ca, sa);
    BFLY2(zrB, ziB, 1, 3, cb, sb); BFLY2(zrB, ziB, 5, 7, cb, sb);
  }
  // stage s=9 (half=256): pairs (r, r^4), pos = (r&3)*64 + lane
  {
    const float ca = tw9a.x, sa = tw9a.y;
    const float cb = tw9b.x, sb = tw9b.y;
    const float cc = tw9c.x, sc = tw9c.y;
    const float cd = tw9d.x, sd = tw9d.y;
    BFLY2(zrA, ziA, 0, 4, ca, sa); BFLY2(zrA, ziA, 1, 5, cb, sb);
    BFLY2(zrA, ziA, 2, 6, cc, sc); BFLY2(zrA, ziA, 3, 7, cd, sd);
    BFLY2(zrB, ziB, 0, 4, ca, sa); BFLY2(zrB, ziB, 1, 5, cb, sb);
    BFLY2(zrB, ziB, 2, 6, cc, sc); BFLY2(zrB, ziB, 3, 7, cd, sd);
  }

  // unpack real spectrum (Z_k at r=k>>6, lane=k&63) + Parseval; mirrors batched; table trig.
  float2 twu[8];
  #pragma unroll
  for (int r = 0; r < 8; ++r) twu[r] = twtab[832 + r * 64 + lane];
  const int srcl = (64 - lane) & 63;
  float mrA[8], miA[8], mrB[8], miB[8];
  #pragma unroll
  for (int r = 0; r < 8; ++r) {
    mrA[r] = __shfl(zrA[7 - r], srcl); miA[r] = __shfl(ziA[7 - r], srcl);
    mrB[r] = __shfl(zrB[7 - r], srcl); miB[r] = __shfl(ziB[7 - r], srcl);
  }
  if (lane == 0) {
    #pragma unroll
    for (int r = 0; r < 8; ++r) {
      mrA[r] = zrA[(8 - r) & 7]; miA[r] = ziA[(8 - r) & 7];
      mrB[r] = zrB[(8 - r) & 7]; miB[r] = ziB[(8 - r) & 7];
    }
  }
  float pA = 0.f, pB = 0.f;
  #pragma unroll
  for (int r = 0; r < 8; ++r) {
    const int k = r * 64 + lane;
    const float c = twu[r].x, sn = twu[r].y;
    const float w = pw_par[k];
    {
      const float er = 0.5f * (zrA[r] + mrA[r]);
      const float ei = 0.5f * (ziA[r] - miA[r]);
      const float orr = 0.5f * (ziA[r] + miA[r]);
      const float oi = -0.5f * (zrA[r] - mrA[r]);
      const float xr = er + orr * c - oi * sn;
      const float xi = ei + orr * sn + oi * c;
      pA += w * (xr * xr + xi * xi);
    }
    {
      const float er = 0.5f * (zrB[r] + mrB[r]);
      const float ei = 0.5f * (ziB[r] - miB[r]);
      const float orr = 0.5f * (ziB[r] + miB[r]);
      const float oi = -0.5f * (zrB[r] - mrB[r]);
      const float xr = er + orr * c - oi * sn;
      const float xi = ei + orr * sn + oi * c;
      pB += w * (xr * xr + xi * xi);
    }
  }
  if (lane == 0) {
    const float w512 = pw_par[512];
    const float xA = zrA[0] - ziA[0];
    const float xB = zrB[0] - ziB[0];
    pA += w512 * xA * xA;
    pB += w512 * xB * xB;
  }
  #pragma unroll
  for (int o = 32; o; o >>= 1) { pA += __shfl_xor(pA, o); pB += __shfl_xor(pB, o); }
  if (lane == 0) { u2[rowA] = pA; u2[rowB] = pB; }
}

__device__ __forceinline__ float gamma_from_u2(float U2, float tv) {
  const float sc = 0.01f;      // sqrt(1e-4)
  const float c = 1e-4f;
  float nrm = sqrtf(U2);
  float nu = fmaxf(nrm, 1e-7f);
  float su = fminf(fmaxf(sc * nu, 1e-7f), 1.f - 1e-5f);
  float Af = tanhf((1.f - tv) * atanhf(su)) / (sc * nu);
  float nvn = fmaxf(fabsf(tv) * nrm, 1e-7f);
  float svv = fminf(fmaxf(sc * nvn, 1e-7f), 1.f - 1e-5f);
  float Bf = tv * tanhf(tv * atanhf(svv)) / (sc * nvn);
  float x2s = Af * Af * U2, y2s = Bf * Bf * U2, xys = Af * Bf * U2;
  float numc = (1.f + 2.f * c * xys + c * y2s) * Af + (1.f - c * x2s) * Bf;
  float den = fmaxf(1.f + 2.f * c * xys + c * c * x2s * y2s, 1e-7f);
  return numc / den;
}

// ---------------- GEMM3: out = gamma(u2[row]) * scale * (comp @ W2^T), fp32 out ----------------
// grid 512 (XCD-swizzled); dbuf LDS 64KB -> 2 blocks/CU.
__global__ __launch_bounds__(256, 2) void k_gemm23(const unsigned short* __restrict__ comp,
                                                   const unsigned short* __restrict__ W2,
                                                   const float* __restrict__ u2,
                                                   const float* __restrict__ t_ptr,
                                                   const float* __restrict__ scale_ptr,
                                                   float* __restrict__ out) {
  __shared__ __align__(16) unsigned short As[2][128 * 64];   // 32 KB
  __shared__ __align__(16) unsigned short Bs[2][128 * 64];   // 32 KB
  __shared__ float gs[128];
  const int tid = threadIdx.x;
  const int lane = tid & 63;
  const int wave = tid >> 6;
  const int xcd = blockIdx.x & 7;
  const int j = blockIdx.x >> 3;          // 0..63
  const int ntile = j & 7;                // 8 n-tiles of 128 share one A-tile per xcd
  const int bmIdx = xcd + 8 * (j >> 3);   // 0..63
  const int bm = bmIdx * 128;
  const int bn = ntile * 128;
  const int mrow = lane & 15;
  const int kq = lane >> 4;
  const int sw = mrow & 7;
  const int mhalf = (wave & 1) * 64;
  const int nhalf = (wave >> 1) * 64;
  const int ar = tid >> 3;
  const int ac = (((tid & 7) ^ (ar & 7))) * 8;
  const unsigned short* Abase = comp + (size_t)(bm + ar) * 1024 + ac;
  const unsigned short* Bbase = W2 + (size_t)(bn + ar) * 1024 + ac;

  // per-row gamma*scale for this block's 128 rows (u2 ready from k_ln);
  // ds_write retires with the first compute's lgkm waits; read only in epilogue.
  if (tid < 128) gs[tid] = gamma_from_u2(u2[bm + tid], t_ptr[0]) * scale_ptr[0];

  f32x4 acc[4][4] = {};

#define G3_STAGE(KT, BUF)                                                                     \
  { const int k0_ = (KT) * 64;                                                                \
    _Pragma("unroll")                                                                         \
    for (int r = 0; r < 4; ++r) {                                                             \
      __builtin_amdgcn_global_load_lds(                                                       \
          (const __attribute__((address_space(1))) void*)(Abase + (size_t)(r * 32) * 1024 + k0_), \
          (__attribute__((address_space(3))) void*)((char*)As[BUF] + r * 4096 + wave * 1024), 16, 0, 0); \
      __builtin_amdgcn_global_load_lds(                                                       \
          (const __attribute__((address_space(1))) void*)(Bbase + (size_t)(r * 32) * 1024 + k0_), \
          (__attribute__((address_space(3))) void*)((char*)Bs[BUF] + r * 4096 + wave * 1024), 16, 0, 0); } }

#define G3_COMP(BUF)                                                                          \
  { const char* AsB = (const char*)As[BUF];                                                   \
    const char* BsB = (const char*)Bs[BUF];                                                   \
    _Pragma("unroll")                                                                         \
    for (int kc = 0; kc < 2; ++kc) {                                                          \
      const int chunk = (kc << 2) | kq;                                                       \
      bf16x8 af[4], bfr[4];                                                                   \
      _Pragma("unroll")                                                                       \
      for (int mt = 0; mt < 4; ++mt)                                                          \
        af[mt] = *(const bf16x8*)(AsB + (mhalf + mt * 16 + mrow) * 128 + ((chunk ^ sw) << 4)); \
      _Pragma("unroll")                                                                       \
      for (int nt = 0; nt < 4; ++nt)                                                          \
        bfr[nt] = *(const bf16x8*)(BsB + (nhalf + nt * 16 + mrow) * 128 + ((chunk ^ sw) << 4)); \
      _Pragma("unroll")                                                                       \
      for (int mt = 0; mt < 4; ++mt)                                                          \
        _Pragma("unroll")                                                                     \
        for (int nt = 0; nt < 4; ++nt)                                                        \
          acc[mt][nt] = __builtin_amdgcn_mfma_f32_16x16x32_bf16(af[mt], bfr[nt], acc[mt][nt], 0, 0, 0); } }

  G3_STAGE(0, 0);
  #pragma unroll 1
  for (int kt = 0; kt < 14; kt += 2) {
    G3_STAGE(kt + 1, 1); GB_WAITV(8); GB_BARRIER; G3_COMP(0); GB_BARRIER;
    G3_STAGE(kt + 2, 0); GB_WAITV(8); GB_BARRIER; G3_COMP(1); GB_BARRIER;
  }
  G3_STAGE(15, 1); GB_WAITV(8); GB_BARRIER; G3_COMP(0); GB_BARRIER;
  GB_WAITV(0); GB_BARRIER; G3_COMP(1);

  const int col = bn + (wave >> 1) * 64 + (lane & 15);
  const int rbase = bm + (wave & 1) * 64 + (lane >> 4) * 4;
  #pragma unroll
  for (int mt = 0; mt < 4; ++mt)
    #pragma unroll
    for (int r = 0; r < 4; ++r) {
      const int row = rbase + mt * 16 + r;
      const float gsc = gs[row - bm];
      #pragma unroll
      for (int nt = 0; nt < 4; ++nt)
        out[(size_t)row * 1024 + (col + nt * 16)] = acc[mt][nt][r] * gsc;
    }
}

extern "C" void kernel_launch(void* const* d_in, const int* in_sizes, int n_in,
                              void* d_out, int out_size, void* d_ws, size_t ws_size,
                              hipStream_t stream) {
  const float* x      = (const float*)d_in[0];
  const float* proj_w = (const float*)d_in[1];
  const float* ln_g   = (const float*)d_in[2];
  const float* ln_b   = (const float*)d_in[3];
  const float* freq_w = (const float*)d_in[4];
  const float* t_p    = (const float*)d_in[5];
  const float* down_w = (const float*)d_in[6];
  const float* scale  = (const float*)d_in[7];

  char* ws = (char*)d_ws;
  unsigned short* xb   = (unsigned short*)ws;                 // 16 MB
  unsigned short* pwb  = (unsigned short*)(ws + (16u << 20)); // 2 MB
  unsigned short* dwb  = (unsigned short*)(ws + (18u << 20)); // 2 MB
  unsigned short* comp = (unsigned short*)(ws + (20u << 20)); // 16 MB
  unsigned short* Sb   = (unsigned short*)(ws + (36u << 20)); // 2 MB
  unsigned short* W2   = (unsigned short*)(ws + (38u << 20)); // 2 MB
  float* s_buf         = (float*)(ws + (40u << 20));          // 4 KB
  float* pw_par        = (float*)(ws + (40u << 20) + 4096);   // ~2 KB
  float* u2            = (float*)(ws + (40u << 20) + 8192);   // 32 KB
  float2* twtab        = (float2*)(ws + (40u << 20) + 8192 + 32768);  // ~11 KB

  k_s<<<32, 256, 0, stream>>>(freq_w, s_buf, pw_par);
  k_prep<<<11270, 256, 0, stream>>>(x, proj_w, down_w, s_buf, xb, pwb, dwb, Sb, twtab);
  k_gemm1w2<<<768, 256, 0, stream>>>(xb, pwb, dwb, Sb, comp, W2);
  k_ln<<<1024, 256, 0, stream>>>(comp, ln_g, ln_b, pw_par, twtab, u2);
  k_gemm23<<<512, 256, 0, stream>>>(comp, W2, u2, t_p, scale, (float*)d_out);
}